// Round 6
// baseline (503.081 us; speedup 1.0000x reference)
//
#include <hip/hip_runtime.h>
#include <hip/hip_bf16.h>
#include <cstdint>

#define N_NODES 100000
#define N_EDGES 1600000
#define N_GRAPHS 64
#define IN_DIM 256
#define HD1 128
#define HD2 256
#define OUT_DIM 512

// CSR-build radix partition parameters
#define NBUCK 196          // ceil(100000/512) buckets of 512 dst nodes
#define NBLK  196          // edge-chunk blocks
#define EPB   8192         // edges per block (NBLK*EPB >= N_EDGES)

typedef __bf16 bf16x8 __attribute__((ext_vector_type(8)));
typedef float f32x4 __attribute__((ext_vector_type(4)));

static __device__ __forceinline__ float bflo(uint32_t v) { return __uint_as_float(v << 16); }
static __device__ __forceinline__ float bfhi(uint32_t v) { return __uint_as_float(v & 0xffff0000u); }
static __device__ __forceinline__ uint32_t f2bf_bits(float f) {
    uint32_t u = __float_as_uint(f);
    return (u + 0x7fffu + ((u >> 16) & 1u)) >> 16;   // RNE
}
static __device__ __forceinline__ uint32_t packbf(float a, float b) {
    return f2bf_bits(a) | (f2bf_bits(b) << 16);
}
static __device__ __forceinline__ float bf2f(uint16_t b) { return __uint_as_float(((uint32_t)b) << 16); }

// ---------------- runtime dtype probe ----------------
// flags[0]: 1 if float tensors are bf16, 0 if float32
// flags[1]: index shift — 0 if ints are int32, 1 if int64 (read low word at i<<1)
__global__ void k_probe(const uint32_t* __restrict__ xw, const int* __restrict__ ei,
                        int* __restrict__ flags) {
    if (threadIdx.x != 0 || blockIdx.x != 0) return;
    int mid = 0;
    for (int i = 0; i < 64; i++) {
        uint32_t f = (xw[i] >> 23) & 0xFF;          // f32 exponent field
        if (f >= 64 && f < 200) mid++;              // plausible-normal-f32 band
    }
    flags[0] = (mid < 32) ? 1 : 0;                  // few plausible f32 words -> bf16
    int nz = 0;
    for (int i = 0; i < 64; i++) if (ei[2 * i + 1] != 0) nz++;
    flags[1] = (nz == 0) ? 1 : 0;                   // all odd words zero -> int64
}

static __device__ __forceinline__ int ld_idx(const int* p, int i, int sh) { return p[i << sh]; }
static __device__ __forceinline__ float ld_f(const void* p, int i, int isbf) {
    return isbf ? bf2f(((const uint16_t*)p)[i]) : ((const float*)p)[i];
}

// ---------------- fused weight/bias canonicalization (bf16, transposed) ----------------
__global__ __launch_bounds__(256) void k_prep(const void* __restrict__ W1, const void* __restrict__ W2,
                                              const void* __restrict__ fcW, const void* __restrict__ b1,
                                              const void* __restrict__ b2, const void* __restrict__ fcb,
                                              uint16_t* __restrict__ W1T, uint16_t* __restrict__ W2T,
                                              uint16_t* __restrict__ fcWc, uint16_t* __restrict__ bc1,
                                              uint16_t* __restrict__ bc2, uint16_t* __restrict__ fcbc,
                                              const int* __restrict__ flags) {
    int i = blockIdx.x * 256 + threadIdx.x;
    int isbf = flags[0];
    if (i < 32768) {                                   // W1T[n][k] = W1[k][n], [128][256]
        int n = i / IN_DIM, k = i % IN_DIM;
        W1T[i] = (uint16_t)f2bf_bits(ld_f(W1, k * HD1 + n, isbf));
    } else if (i < 65536) {                            // W2T[n][k] = W2[k][n], [256][128]
        int j = i - 32768;
        int n = j / HD1, k = j % HD1;
        W2T[j] = (uint16_t)f2bf_bits(ld_f(W2, k * HD2 + n, isbf));
    } else if (i < 196608) {
        int j = i - 65536;
        fcWc[j] = (uint16_t)f2bf_bits(ld_f(fcW, j, isbf));
    } else if (i < 196736) {
        bc1[i - 196608] = (uint16_t)f2bf_bits(ld_f(b1, i - 196608, isbf));
    } else if (i < 196992) {
        bc2[i - 196736] = (uint16_t)f2bf_bits(ld_f(b2, i - 196736, isbf));
    } else if (i < 197504) {
        fcbc[i - 196992] = (uint16_t)f2bf_bits(ld_f(fcb, i - 196992, isbf));
    }
}

// ---------------- CSR build: atomic-free radix partition by dst bucket ----------------

__global__ __launch_bounds__(256) void k_hist(const int* __restrict__ ei, int* __restrict__ bh,
                                              const int* __restrict__ flags) {
    __shared__ int h[NBUCK];
    int t = threadIdx.x, blk = blockIdx.x;
    if (t < NBUCK) h[t] = 0;
    __syncthreads();
    int sh = flags[1];
    int base = blk * EPB;
#pragma unroll
    for (int k = 0; k < EPB / 256; k++) {
        int e = base + k * 256 + t;
        if (e < N_EDGES) atomicAdd(&h[ld_idx(ei, N_EDGES + e, sh) >> 9], 1);
    }
    __syncthreads();
    if (t < NBUCK) bh[blk * NBUCK + t] = h[t];
}

__global__ __launch_bounds__(256) void k_colscan(const int* __restrict__ bh, int* __restrict__ bhoff,
                                                 int* __restrict__ bucket_cnt) {
    __shared__ int s[256];
    int b = blockIdx.x, t = threadIdx.x;
    int v = (t < NBLK) ? bh[t * NBUCK + b] : 0;
    s[t] = v; __syncthreads();
    for (int off = 1; off < 256; off <<= 1) {
        int x = (t >= off) ? s[t - off] : 0;
        __syncthreads();
        s[t] += x;
        __syncthreads();
    }
    if (t < NBLK) bhoff[t * NBUCK + b] = s[t] - v;    // exclusive within bucket
    if (t == 255) bucket_cnt[b] = s[255];
}

__global__ __launch_bounds__(256) void k_bscan(const int* __restrict__ bucket_cnt,
                                               int* __restrict__ bucket_base,
                                               int* __restrict__ row_ptr) {
    __shared__ int s[256];
    int t = threadIdx.x;
    int v = (t < NBUCK) ? bucket_cnt[t] : 0;
    s[t] = v; __syncthreads();
    for (int off = 1; off < 256; off <<= 1) {
        int x = (t >= off) ? s[t - off] : 0;
        __syncthreads();
        s[t] += x;
        __syncthreads();
    }
    if (t < NBUCK) bucket_base[t] = s[t] - v;
    if (t == NBUCK - 1) { bucket_base[NBUCK] = s[t]; row_ptr[N_NODES] = s[t]; }
}

__global__ __launch_bounds__(256) void k_part(const int* __restrict__ ei,
                                              const int* __restrict__ bucket_base,
                                              const int* __restrict__ bhoff,
                                              int* __restrict__ tmp,
                                              const int* __restrict__ flags) {
    __shared__ int cur[NBUCK];
    int t = threadIdx.x, blk = blockIdx.x;
    if (t < NBUCK) cur[t] = bucket_base[t] + bhoff[blk * NBUCK + t];
    __syncthreads();
    int sh = flags[1];
    int base = blk * EPB;
#pragma unroll
    for (int k = 0; k < EPB / 256; k++) {
        int e = base + k * 256 + t;
        if (e < N_EDGES) {
            int s = ld_idx(ei, e, sh), d = ld_idx(ei, N_EDGES + e, sh);
            int pos = atomicAdd(&cur[d >> 9], 1);
            tmp[pos] = (s << 9) | (d & 511);          // s<2^17 -> 26-bit key
        }
    }
}

__global__ __launch_bounds__(256) void k_bsort(const int* __restrict__ tmp,
                                               const int* __restrict__ bucket_base,
                                               int* __restrict__ csr_src,
                                               int* __restrict__ row_ptr,
                                               float* __restrict__ dinv) {
    __shared__ int h[512], a[512], c[512];
    int b = blockIdx.x, t = threadIdx.x;
    int beg = bucket_base[b], end = bucket_base[b + 1];
    h[t] = 0; h[t + 256] = 0;
    __syncthreads();
    for (int i = beg + t; i < end; i += 256) atomicAdd(&h[tmp[i] & 511], 1);
    __syncthreads();
    a[t] = h[t]; a[t + 256] = h[t + 256];
    __syncthreads();
    for (int off = 1; off < 512; off <<= 1) {         // inclusive Hillis-Steele, 2 elems/thread
        int x0 = (t >= off) ? a[t - off] : 0;
        int x1 = ((t + 256) >= off) ? a[t + 256 - off] : 0;
        __syncthreads();
        a[t] += x0; a[t + 256] += x1;
        __syncthreads();
    }
#pragma unroll
    for (int u = 0; u < 2; u++) {
        int i = t + u * 256;
        int node = (b << 9) + i;
        int ex = a[i] - h[i];                         // exclusive prefix
        if (node < N_NODES) {
            row_ptr[node] = beg + ex;
            dinv[node] = rsqrtf((float)(h[i] + 1));   // +1 self-loop
        }
        c[i] = ex;
    }
    __syncthreads();
    for (int i = beg + t; i < end; i += 256) {
        int e = tmp[i];
        int pos = atomicAdd(&c[e & 511], 1);
        csr_src[beg + pos] = e >> 9;                  // writes confined to this bucket's region
    }
}

// ---------------- per-graph node counts (run-length + LDS histogram) ----------------
#define GCNT_CHUNK 8
__global__ __launch_bounds__(256) void k_gcnt(const int* __restrict__ bat, int* __restrict__ gcnt,
                                              const int* __restrict__ flags) {
    __shared__ int h[N_GRAPHS];
    int t = threadIdx.x;
    if (t < N_GRAPHS) h[t] = 0;
    __syncthreads();
    int sh = flags[1];
    int base = (blockIdx.x * 256 + t) * GCNT_CHUNK;
    int cur = -1, run = 0;
#pragma unroll
    for (int u = 0; u < GCNT_CHUNK; u++) {
        int i = base + u;
        if (i < N_NODES) {
            int g = ld_idx(bat, i, sh);
            if (g == cur) run++;
            else { if (run) atomicAdd(&h[cur], run); cur = g; run = 1; }
        }
    }
    if (run) atomicAdd(&h[cur], run);
    __syncthreads();
    if (t < N_GRAPHS) { int v = h[t]; if (v) atomicAdd(&gcnt[t], v); }
}

// ---------------- GEMM-1: Y1[M,128] = X[M,256] @ W1, dual-dtype A ----------------
// 16 rows per wave (64 rows/block) for 2x wave-level parallelism vs 32-row tiles.

__global__ __launch_bounds__(256) void k_gemm1(const void* __restrict__ Ain,
                                               const uint16_t* __restrict__ BT,  // [128][256] bf16
                                               uint16_t* __restrict__ C,
                                               const int* __restrict__ flags) {
    const int M = N_NODES, K = IN_DIM, N = HD1;
    int isbf = flags[0];
    int wave = threadIdx.x >> 6, lane = threadIdx.x & 63;
    int quad = lane >> 4, l16 = lane & 15;
    int m0 = blockIdx.x * 64 + wave * 16;

    f32x4 acc[8];
#pragma unroll
    for (int b = 0; b < 8; b++) acc[b] = f32x4{0.f, 0.f, 0.f, 0.f};

    int arow = m0 + l16; arow = arow < M ? arow : M - 1;   // clamp; store guarded

#pragma unroll
    for (int k0 = 0; k0 < K; k0 += 32) {
        bf16x8 af, bq[8];
        int off = arow * K + k0 + quad * 8;
        if (isbf) {
            af = *(const bf16x8*)((const uint16_t*)Ain + off);
        } else {
            const float* p = (const float*)Ain + off;
            f32x4 f0 = *(const f32x4*)p, f1 = *(const f32x4*)(p + 4);
            union { uint16_t u[8]; bf16x8 v; } r;
#pragma unroll
            for (int j = 0; j < 4; j++) {
                r.u[j]     = (uint16_t)f2bf_bits(f0[j]);
                r.u[4 + j] = (uint16_t)f2bf_bits(f1[j]);
            }
            af = r.v;
        }
#pragma unroll
        for (int nt = 0; nt < 8; nt++) {
            int col = nt * 16 + l16;
            bq[nt] = *(const bf16x8*)(BT + col * K + k0 + quad * 8);
        }
#pragma unroll
        for (int nt = 0; nt < 8; nt++)
            acc[nt] = __builtin_amdgcn_mfma_f32_16x16x32_bf16(af, bq[nt], acc[nt], 0, 0, 0);
    }

#pragma unroll
    for (int reg = 0; reg < 4; reg++) {
        int row = m0 + quad * 4 + reg;                // C/D: col=lane&15, row=quad*4+reg
        if (row < M)
#pragma unroll
            for (int nt = 0; nt < 8; nt++)
                C[row * N + nt * 16 + l16] = (uint16_t)f2bf_bits(acc[nt][reg]);
    }
}

// ---------------- aggregation (wave-cooperative, 8-deep gather MLP) ----------------
// out[d] = dinv[d] * (sum_src dinv[s]*Y[s] + dinv[d]*Y[d]) [+bias, relu]

template <int WITH_BIAS_RELU>
__global__ __launch_bounds__(256) void k_agg(const uint16_t* __restrict__ Yin, uint16_t* __restrict__ Yout,
                                             const int* __restrict__ row_ptr, const int* __restrict__ csr_src,
                                             const float* __restrict__ dinv, const uint16_t* __restrict__ bias) {
    int node = blockIdx.x * 4 + (threadIdx.x >> 6);
    int l = threadIdx.x & 63;
    const uint32_t* Y32 = (const uint32_t*)Yin;

    float wd = dinv[node];
    uint32_t v = Y32[(size_t)node * 64 + l];
    float a0 = wd * bflo(v), a1 = wd * bfhi(v);

    int e0 = row_ptr[node], e1 = row_ptr[node + 1];
    for (int cb = e0; cb < e1; cb += 64) {
        int cnt = e1 - cb; if (cnt > 64) cnt = 64;
        int my_src = 0; float my_w = 0.f;
        if (l < cnt) { my_src = csr_src[cb + l]; my_w = dinv[my_src]; }
        int rounds = (cnt + 7) >> 3;                  // padded lanes have w=0 -> contribute 0
        for (int r = 0; r < rounds; r++) {
            int jb = r * 8;
            int s[8]; float w[8]; uint32_t vv[8];
#pragma unroll
            for (int t = 0; t < 8; t++) { s[t] = __shfl(my_src, jb + t); w[t] = __shfl(my_w, jb + t); }
#pragma unroll
            for (int t = 0; t < 8; t++) vv[t] = Y32[(size_t)s[t] * 64 + l];
#pragma unroll
            for (int t = 0; t < 8; t++) { a0 += w[t] * bflo(vv[t]); a1 += w[t] * bfhi(vv[t]); }
        }
    }
    a0 *= wd; a1 *= wd;
    if (WITH_BIAS_RELU) {
        a0 = fmaxf(a0 + bf2f(bias[2 * l]), 0.f);
        a1 = fmaxf(a1 + bf2f(bias[2 * l + 1]), 0.f);
    }
    ((uint32_t*)Yout)[(size_t)node * 64 + l] = packbf(a0, a1);
}

// ---------------- GEMM-2 + fused bias/relu/pool: pooled[g] += relu(Z@W2 + b2) ----------------
// 16 rows per wave (64 rows/block), grid (1563, 2).

__global__ __launch_bounds__(256) void k_gemm2_pool(const uint16_t* __restrict__ A,   // Zb [M][128]
                                                    const uint16_t* __restrict__ BT,  // W2T [256][128]
                                                    const uint16_t* __restrict__ bias,// bc2 [256]
                                                    const int* __restrict__ bat,
                                                    const int* __restrict__ flags,
                                                    float* __restrict__ pooled) {
    const int M = N_NODES, K = HD1;
    int wave = threadIdx.x >> 6, lane = threadIdx.x & 63;
    int quad = lane >> 4, l16 = lane & 15;
    int m0 = blockIdx.x * 64 + wave * 16;
    int n0 = blockIdx.y * 128;

    f32x4 acc[8];
#pragma unroll
    for (int b = 0; b < 8; b++) acc[b] = f32x4{0.f, 0.f, 0.f, 0.f};

    int arow = m0 + l16; arow = arow < M ? arow : M - 1;

#pragma unroll
    for (int k0 = 0; k0 < K; k0 += 32) {
        bf16x8 af, bq[8];
        af = *(const bf16x8*)(A + arow * K + k0 + quad * 8);
#pragma unroll
        for (int nt = 0; nt < 8; nt++) {
            int col = n0 + nt * 16 + l16;
            bq[nt] = *(const bf16x8*)(BT + col * K + k0 + quad * 8);
        }
#pragma unroll
        for (int nt = 0; nt < 8; nt++)
            acc[nt] = __builtin_amdgcn_mfma_f32_16x16x32_bf16(af, bq[nt], acc[nt], 0, 0, 0);
    }

    int sh = flags[1];
    float bv[8];
#pragma unroll
    for (int nt = 0; nt < 8; nt++) bv[nt] = bf2f(bias[n0 + nt * 16 + l16]);

    // M % 16 == 0 -> a wave's 16 rows are all-valid or all-invalid.
    if (m0 < M) {
        int gfirst = ld_idx(bat, m0, sh);
        int glast  = ld_idx(bat, m0 + 15, sh);
        if (gfirst == glast) {
            // whole wave one graph: reduce 4 regs in-register, 4 quads via shfl_xor,
            // one atomic per (nt,l16) from quad-0 lanes: 128 atomics/wave vs 512.
#pragma unroll
            for (int nt = 0; nt < 8; nt++) {
                float s = 0.f;
#pragma unroll
                for (int reg = 0; reg < 4; reg++)
                    s += fmaxf(acc[nt][reg] + bv[nt], 0.f);
                s += __shfl_xor(s, 16);
                s += __shfl_xor(s, 32);
                if (quad == 0)
                    atomicAdd(&pooled[gfirst * HD2 + n0 + nt * 16 + l16], s);
            }
        } else {
            int rb = m0 + quad * 4;
#pragma unroll
            for (int reg = 0; reg < 4; reg++) {
                int g = ld_idx(bat, rb + reg, sh);
#pragma unroll
                for (int nt = 0; nt < 8; nt++)
                    atomicAdd(&pooled[g * HD2 + n0 + nt * 16 + l16],
                              fmaxf(acc[nt][reg] + bv[nt], 0.f));
            }
        }
    }
}

// ---------------- final FC: out = relu(mean @ fcW + fcb), dual-dtype out ----------------

__global__ __launch_bounds__(512) void k_final(const float* __restrict__ pooled, const int* __restrict__ gcnt,
                                               const uint16_t* __restrict__ fcWc, const uint16_t* __restrict__ fcbc,
                                               void* __restrict__ out, const int* __restrict__ flags) {
    __shared__ float pm[HD2];
    int g = blockIdx.x, t = threadIdx.x;
    if (t < HD2) pm[t] = pooled[g * HD2 + t] / fmaxf((float)gcnt[g], 1.0f);
    __syncthreads();
    float acc = bf2f(fcbc[t]);
    for (int k = 0; k < HD2; k++) acc = fmaf(pm[k], bf2f(fcWc[k * OUT_DIM + t]), acc);
    acc = fmaxf(acc, 0.f);
    if (flags[0]) ((uint16_t*)out)[g * OUT_DIM + t] = (uint16_t)f2bf_bits(acc);
    else          ((float*)out)[g * OUT_DIM + t] = acc;
}

// ---------------- launcher ----------------

extern "C" void kernel_launch(void* const* d_in, const int* in_sizes, int n_in,
                              void* d_out, int out_size, void* d_ws, size_t ws_size,
                              hipStream_t stream) {
    const void* x   = d_in[0];               // [100000,256] bf16 or f32
    const int*  ei  = (const int*)d_in[1];   // [2,1600000] int32 or int64
    const int*  bat = (const int*)d_in[2];   // [100000]
    const void* W1  = d_in[3];               // [256,128]
    const void* b1  = d_in[4];               // [128]
    const void* W2  = d_in[5];               // [128,256]
    const void* b2  = d_in[6];               // [256]
    const void* fcW = d_in[7];               // [256,512]
    const void* fcb = d_in[8];               // [512]

    char* ws = (char*)d_ws;
    size_t off = 0;
    auto alloc = [&](size_t bytes) -> void* {
        void* p = ws + off;
        off += (bytes + 255) & ~(size_t)255;
        return p;
    };
    uint16_t* buf0 = (uint16_t*)alloc((size_t)N_NODES * HD1 * 2);   // Y1, later Zb
    uint16_t* Hb   = (uint16_t*)alloc((size_t)N_NODES * HD1 * 2);
    int*   row_ptr = (int*)alloc((N_NODES + 1) * 4);
    int*   csr_src = (int*)alloc((size_t)N_EDGES * 4);
    int*   tmp     = (int*)alloc((size_t)N_EDGES * 4);
    int*   bh      = (int*)alloc(NBLK * NBUCK * 4);
    int*   bhoff   = (int*)alloc(NBLK * NBUCK * 4);
    int*   bucket_cnt  = (int*)alloc(NBUCK * 4);
    int*   bucket_base = (int*)alloc((NBUCK + 1) * 4);
    float* dinv    = (float*)alloc(N_NODES * 4);
    int*   gcnt    = (int*)alloc(N_GRAPHS * 4);
    float* pooled  = (float*)alloc(N_GRAPHS * HD2 * 4);
    uint16_t* W1T  = (uint16_t*)alloc(IN_DIM * HD1 * 2);
    uint16_t* W2T  = (uint16_t*)alloc(HD1 * HD2 * 2);
    uint16_t* bc1  = (uint16_t*)alloc(HD1 * 2);
    uint16_t* bc2  = (uint16_t*)alloc(HD2 * 2);
    uint16_t* fcWc = (uint16_t*)alloc(HD2 * OUT_DIM * 2);
    uint16_t* fcbc = (uint16_t*)alloc(OUT_DIM * 2);
    int*   flags   = (int*)alloc(64 * 4);

    uint16_t* Y1 = buf0;
    uint16_t* Zb = buf0;   // Y1 dead after agg-1

    hipMemsetAsync(gcnt, 0, N_GRAPHS * 4, stream);
    hipMemsetAsync(pooled, 0, N_GRAPHS * HD2 * 4, stream);

    k_probe<<<1, 64, 0, stream>>>((const uint32_t*)x, ei, flags);

    // canonicalize weights/biases to bf16 (one fused kernel)
    k_prep<<<(197504 + 255) / 256, 256, 0, stream>>>(W1, W2, fcW, b1, b2, fcb,
                                                     W1T, W2T, fcWc, bc1, bc2, fcbc, flags);

    // CSR build: hist -> colscan -> bscan -> part -> bucket sort (no global atomics)
    k_hist<<<NBLK, 256, 0, stream>>>(ei, bh, flags);
    k_colscan<<<NBUCK, 256, 0, stream>>>(bh, bhoff, bucket_cnt);
    k_bscan<<<1, 256, 0, stream>>>(bucket_cnt, bucket_base, row_ptr);
    k_part<<<NBLK, 256, 0, stream>>>(ei, bucket_base, bhoff, tmp, flags);
    k_bsort<<<NBUCK, 256, 0, stream>>>(tmp, bucket_base, csr_src, row_ptr, dinv);

    k_gcnt<<<(N_NODES + 256 * GCNT_CHUNK - 1) / (256 * GCNT_CHUNK), 256, 0, stream>>>(bat, gcnt, flags);

    // layer 1: Y1 = X @ W1 ; H = relu(A Y1 + b1)
    k_gemm1<<<(N_NODES + 63) / 64, 256, 0, stream>>>(x, W1T, Y1, flags);
    k_agg<1><<<N_NODES / 4, 256, 0, stream>>>(Y1, Hb, row_ptr, csr_src, dinv, bc1);

    // layer 2 (aggregate-first): Z = A H ; pooled += relu(Z @ W2 + b2)
    k_agg<0><<<N_NODES / 4, 256, 0, stream>>>(Hb, Zb, row_ptr, csr_src, dinv, nullptr);
    k_gemm2_pool<<<dim3((N_NODES + 63) / 64, 2), 256, 0, stream>>>(Zb, W2T, bc2, bat, flags, pooled);

    // final FC
    k_final<<<N_GRAPHS, 512, 0, stream>>>(pooled, gcnt, fcWc, fcbc, d_out, flags);
}

// Round 7
// 421.097 us; speedup vs baseline: 1.1947x; 1.1947x over previous
//
#include <hip/hip_runtime.h>
#include <hip/hip_bf16.h>
#include <cstdint>

#define N_NODES 100000
#define N_EDGES 1600000
#define N_GRAPHS 64
#define IN_DIM 256
#define HD1 128
#define HD2 256
#define OUT_DIM 512

// CSR-build radix partition parameters
#define NBUCK 196          // ceil(100000/512) buckets of 512 dst nodes
#define NBLK  196          // edge-chunk blocks
#define EPB   8192         // edges per block (NBLK*EPB >= N_EDGES)

// LDS B-tile row pitch (elements): 128 + 8 pad -> 68-dword stride -> balanced banks
#define BPAD 136

typedef __bf16 bf16x8 __attribute__((ext_vector_type(8)));
typedef float f32x4 __attribute__((ext_vector_type(4)));

static __device__ __forceinline__ float bflo(uint32_t v) { return __uint_as_float(v << 16); }
static __device__ __forceinline__ float bfhi(uint32_t v) { return __uint_as_float(v & 0xffff0000u); }
static __device__ __forceinline__ uint32_t f2bf_bits(float f) {
    uint32_t u = __float_as_uint(f);
    return (u + 0x7fffu + ((u >> 16) & 1u)) >> 16;   // RNE
}
static __device__ __forceinline__ uint32_t packbf(float a, float b) {
    return f2bf_bits(a) | (f2bf_bits(b) << 16);
}
static __device__ __forceinline__ float bf2f(uint16_t b) { return __uint_as_float(((uint32_t)b) << 16); }

// ---------------- runtime dtype probe ----------------
__global__ void k_probe(const uint32_t* __restrict__ xw, const int* __restrict__ ei,
                        int* __restrict__ flags) {
    if (threadIdx.x != 0 || blockIdx.x != 0) return;
    int mid = 0;
    for (int i = 0; i < 64; i++) {
        uint32_t f = (xw[i] >> 23) & 0xFF;
        if (f >= 64 && f < 200) mid++;
    }
    flags[0] = (mid < 32) ? 1 : 0;                  // bf16 vs f32
    int nz = 0;
    for (int i = 0; i < 64; i++) if (ei[2 * i + 1] != 0) nz++;
    flags[1] = (nz == 0) ? 1 : 0;                   // int64 vs int32
}

static __device__ __forceinline__ int ld_idx(const int* p, int i, int sh) { return p[i << sh]; }
static __device__ __forceinline__ float ld_f(const void* p, int i, int isbf) {
    return isbf ? bf2f(((const uint16_t*)p)[i]) : ((const float*)p)[i];
}

// ---------------- fused weight/bias canonicalization (bf16, transposed) ----------------
__global__ __launch_bounds__(256) void k_prep(const void* __restrict__ W1, const void* __restrict__ W2,
                                              const void* __restrict__ fcW, const void* __restrict__ b1,
                                              const void* __restrict__ b2, const void* __restrict__ fcb,
                                              uint16_t* __restrict__ W1T, uint16_t* __restrict__ W2T,
                                              uint16_t* __restrict__ fcWc, uint16_t* __restrict__ bc1,
                                              uint16_t* __restrict__ bc2, uint16_t* __restrict__ fcbc,
                                              const int* __restrict__ flags) {
    int i = blockIdx.x * 256 + threadIdx.x;
    int isbf = flags[0];
    if (i < 32768) {                                   // W1T[n][k] = W1[k][n], [128][256]
        int n = i / IN_DIM, k = i % IN_DIM;
        W1T[i] = (uint16_t)f2bf_bits(ld_f(W1, k * HD1 + n, isbf));
    } else if (i < 65536) {                            // W2T[n][k] = W2[k][n], [256][128]
        int j = i - 32768;
        int n = j / HD1, k = j % HD1;
        W2T[j] = (uint16_t)f2bf_bits(ld_f(W2, k * HD2 + n, isbf));
    } else if (i < 196608) {
        int j = i - 65536;
        fcWc[j] = (uint16_t)f2bf_bits(ld_f(fcW, j, isbf));
    } else if (i < 196736) {
        bc1[i - 196608] = (uint16_t)f2bf_bits(ld_f(b1, i - 196608, isbf));
    } else if (i < 196992) {
        bc2[i - 196736] = (uint16_t)f2bf_bits(ld_f(b2, i - 196736, isbf));
    } else if (i < 197504) {
        fcbc[i - 196992] = (uint16_t)f2bf_bits(ld_f(fcb, i - 196992, isbf));
    }
}

// ---------------- CSR build: atomic-free radix partition by dst bucket ----------------

__global__ __launch_bounds__(256) void k_hist(const int* __restrict__ ei, int* __restrict__ bh,
                                              const int* __restrict__ flags) {
    __shared__ int h[NBUCK];
    int t = threadIdx.x, blk = blockIdx.x;
    if (t < NBUCK) h[t] = 0;
    __syncthreads();
    int sh = flags[1];
    int base = blk * EPB;
#pragma unroll
    for (int k = 0; k < EPB / 256; k++) {
        int e = base + k * 256 + t;
        if (e < N_EDGES) atomicAdd(&h[ld_idx(ei, N_EDGES + e, sh) >> 9], 1);
    }
    __syncthreads();
    if (t < NBUCK) bh[blk * NBUCK + t] = h[t];
}

__global__ __launch_bounds__(256) void k_colscan(const int* __restrict__ bh, int* __restrict__ bhoff,
                                                 int* __restrict__ bucket_cnt) {
    __shared__ int s[256];
    int b = blockIdx.x, t = threadIdx.x;
    int v = (t < NBLK) ? bh[t * NBUCK + b] : 0;
    s[t] = v; __syncthreads();
    for (int off = 1; off < 256; off <<= 1) {
        int x = (t >= off) ? s[t - off] : 0;
        __syncthreads();
        s[t] += x;
        __syncthreads();
    }
    if (t < NBLK) bhoff[t * NBUCK + b] = s[t] - v;    // exclusive within bucket
    if (t == 255) bucket_cnt[b] = s[255];
}

__global__ __launch_bounds__(256) void k_bscan(const int* __restrict__ bucket_cnt,
                                               int* __restrict__ bucket_base,
                                               int* __restrict__ row_ptr) {
    __shared__ int s[256];
    int t = threadIdx.x;
    int v = (t < NBUCK) ? bucket_cnt[t] : 0;
    s[t] = v; __syncthreads();
    for (int off = 1; off < 256; off <<= 1) {
        int x = (t >= off) ? s[t - off] : 0;
        __syncthreads();
        s[t] += x;
        __syncthreads();
    }
    if (t < NBUCK) bucket_base[t] = s[t] - v;
    if (t == NBUCK - 1) { bucket_base[NBUCK] = s[t]; row_ptr[N_NODES] = s[t]; }
}

__global__ __launch_bounds__(256) void k_part(const int* __restrict__ ei,
                                              const int* __restrict__ bucket_base,
                                              const int* __restrict__ bhoff,
                                              int* __restrict__ tmp,
                                              const int* __restrict__ flags) {
    __shared__ int cur[NBUCK];
    int t = threadIdx.x, blk = blockIdx.x;
    if (t < NBUCK) cur[t] = bucket_base[t] + bhoff[blk * NBUCK + t];
    __syncthreads();
    int sh = flags[1];
    int base = blk * EPB;
#pragma unroll
    for (int k = 0; k < EPB / 256; k++) {
        int e = base + k * 256 + t;
        if (e < N_EDGES) {
            int s = ld_idx(ei, e, sh), d = ld_idx(ei, N_EDGES + e, sh);
            int pos = atomicAdd(&cur[d >> 9], 1);
            tmp[pos] = (s << 9) | (d & 511);          // s<2^17 -> 26-bit key
        }
    }
}

__global__ __launch_bounds__(256) void k_bsort(const int* __restrict__ tmp,
                                               const int* __restrict__ bucket_base,
                                               int* __restrict__ csr_src,
                                               int* __restrict__ row_ptr,
                                               float* __restrict__ dinv) {
    __shared__ int h[512], a[512], c[512];
    int b = blockIdx.x, t = threadIdx.x;
    int beg = bucket_base[b], end = bucket_base[b + 1];
    h[t] = 0; h[t + 256] = 0;
    __syncthreads();
    for (int i = beg + t; i < end; i += 256) atomicAdd(&h[tmp[i] & 511], 1);
    __syncthreads();
    a[t] = h[t]; a[t + 256] = h[t + 256];
    __syncthreads();
    for (int off = 1; off < 512; off <<= 1) {
        int x0 = (t >= off) ? a[t - off] : 0;
        int x1 = ((t + 256) >= off) ? a[t + 256 - off] : 0;
        __syncthreads();
        a[t] += x0; a[t + 256] += x1;
        __syncthreads();
    }
#pragma unroll
    for (int u = 0; u < 2; u++) {
        int i = t + u * 256;
        int node = (b << 9) + i;
        int ex = a[i] - h[i];
        if (node < N_NODES) {
            row_ptr[node] = beg + ex;
            dinv[node] = rsqrtf((float)(h[i] + 1));   // +1 self-loop
        }
        c[i] = ex;
    }
    __syncthreads();
    for (int i = beg + t; i < end; i += 256) {
        int e = tmp[i];
        int pos = atomicAdd(&c[e & 511], 1);
        csr_src[beg + pos] = e >> 9;
    }
}

// ---------------- per-graph node counts ----------------
#define GCNT_CHUNK 8
__global__ __launch_bounds__(256) void k_gcnt(const int* __restrict__ bat, int* __restrict__ gcnt,
                                              const int* __restrict__ flags) {
    __shared__ int h[N_GRAPHS];
    int t = threadIdx.x;
    if (t < N_GRAPHS) h[t] = 0;
    __syncthreads();
    int sh = flags[1];
    int base = (blockIdx.x * 256 + t) * GCNT_CHUNK;
    int cur = -1, run = 0;
#pragma unroll
    for (int u = 0; u < GCNT_CHUNK; u++) {
        int i = base + u;
        if (i < N_NODES) {
            int g = ld_idx(bat, i, sh);
            if (g == cur) run++;
            else { if (run) atomicAdd(&h[cur], run); cur = g; run = 1; }
        }
    }
    if (run) atomicAdd(&h[cur], run);
    __syncthreads();
    if (t < N_GRAPHS) { int v = h[t]; if (v) atomicAdd(&gcnt[t], v); }
}

// ---------------- GEMM-1: Y1[M,128] = X[M,256] @ W1 ----------------
// B staged in LDS (two 32KB K-halves); 32 rows/wave, 128 rows/block.
// Global VMEM stream is pure streaming A; B fetched once per block from L2.

__global__ __launch_bounds__(256) void k_gemm1(const void* __restrict__ Ain,
                                               const uint16_t* __restrict__ BT,  // [128][256] bf16
                                               uint16_t* __restrict__ C,
                                               const int* __restrict__ flags) {
    const int M = N_NODES, K = IN_DIM, N = HD1;
    __shared__ uint16_t Bs[HD1 * BPAD];               // 128 x 136 bf16 = 34 KB
    int isbf = flags[0];
    int t = threadIdx.x;
    int wave = t >> 6, lane = t & 63;
    int quad = lane >> 4, l16 = lane & 15;
    int m0 = blockIdx.x * 128 + wave * 32;

    f32x4 acc[2][8];
#pragma unroll
    for (int a = 0; a < 2; a++)
#pragma unroll
        for (int b = 0; b < 8; b++) acc[a][b] = f32x4{0.f, 0.f, 0.f, 0.f};

    int arow[2];
#pragma unroll
    for (int mt = 0; mt < 2; mt++) {
        int r = m0 + mt * 16 + l16;
        arow[mt] = r < M ? r : M - 1;                 // clamp; store guarded
    }

#pragma unroll
    for (int half = 0; half < 2; half++) {
        int kb = half * 128;
        // stage B[0:128][kb:kb+128] -> Bs (coalesced 16B per thread)
#pragma unroll
        for (int i = 0; i < 8; i++) {
            int flat = (i * 256 + t) * 8;             // 0..16383
            int col = flat >> 7, kk = flat & 127;
            *(bf16x8*)(Bs + col * BPAD + kk) = *(const bf16x8*)(BT + col * K + kb + kk);
        }
        __syncthreads();

        // A fragments for this half: 8 independent HBM loads per wave up-front
        bf16x8 af[2][4];
#pragma unroll
        for (int mt = 0; mt < 2; mt++)
#pragma unroll
            for (int ks = 0; ks < 4; ks++) {
                int off = arow[mt] * K + kb + ks * 32 + quad * 8;
                if (isbf) {
                    af[mt][ks] = *(const bf16x8*)((const uint16_t*)Ain + off);
                } else {
                    const float* p = (const float*)Ain + off;
                    f32x4 f0 = *(const f32x4*)p, f1 = *(const f32x4*)(p + 4);
                    union { uint16_t u[8]; bf16x8 v; } r;
#pragma unroll
                    for (int j = 0; j < 4; j++) {
                        r.u[j]     = (uint16_t)f2bf_bits(f0[j]);
                        r.u[4 + j] = (uint16_t)f2bf_bits(f1[j]);
                    }
                    af[mt][ks] = r.v;
                }
            }

#pragma unroll
        for (int ks = 0; ks < 4; ks++) {
            bf16x8 bq[8];
#pragma unroll
            for (int nt = 0; nt < 8; nt++)
                bq[nt] = *(const bf16x8*)(Bs + (nt * 16 + l16) * BPAD + ks * 32 + quad * 8);
#pragma unroll
            for (int mt = 0; mt < 2; mt++)
#pragma unroll
                for (int nt = 0; nt < 8; nt++)
                    acc[mt][nt] = __builtin_amdgcn_mfma_f32_16x16x32_bf16(af[mt][ks], bq[nt], acc[mt][nt], 0, 0, 0);
        }
        __syncthreads();                              // before next half overwrites Bs
    }

#pragma unroll
    for (int mt = 0; mt < 2; mt++)
#pragma unroll
        for (int reg = 0; reg < 4; reg++) {
            int row = m0 + mt * 16 + quad * 4 + reg;  // C/D: col=lane&15, row=quad*4+reg
            if (row < M)
#pragma unroll
                for (int nt = 0; nt < 8; nt++)
                    C[row * N + nt * 16 + l16] = (uint16_t)f2bf_bits(acc[mt][nt][reg]);
        }
}

// ---------------- aggregation (wave-cooperative, 8-deep gather MLP) ----------------

template <int WITH_BIAS_RELU>
__global__ __launch_bounds__(256) void k_agg(const uint16_t* __restrict__ Yin, uint16_t* __restrict__ Yout,
                                             const int* __restrict__ row_ptr, const int* __restrict__ csr_src,
                                             const float* __restrict__ dinv, const uint16_t* __restrict__ bias) {
    int node = blockIdx.x * 4 + (threadIdx.x >> 6);
    int l = threadIdx.x & 63;
    const uint32_t* Y32 = (const uint32_t*)Yin;

    float wd = dinv[node];
    uint32_t v = Y32[(size_t)node * 64 + l];
    float a0 = wd * bflo(v), a1 = wd * bfhi(v);

    int e0 = row_ptr[node], e1 = row_ptr[node + 1];
    for (int cb = e0; cb < e1; cb += 64) {
        int cnt = e1 - cb; if (cnt > 64) cnt = 64;
        int my_src = 0; float my_w = 0.f;
        if (l < cnt) { my_src = csr_src[cb + l]; my_w = dinv[my_src]; }
        int rounds = (cnt + 7) >> 3;                  // padded lanes have w=0 -> contribute 0
        for (int r = 0; r < rounds; r++) {
            int jb = r * 8;
            int s[8]; float w[8]; uint32_t vv[8];
#pragma unroll
            for (int t = 0; t < 8; t++) { s[t] = __shfl(my_src, jb + t); w[t] = __shfl(my_w, jb + t); }
#pragma unroll
            for (int t = 0; t < 8; t++) vv[t] = Y32[(size_t)s[t] * 64 + l];
#pragma unroll
            for (int t = 0; t < 8; t++) { a0 += w[t] * bflo(vv[t]); a1 += w[t] * bfhi(vv[t]); }
        }
    }
    a0 *= wd; a1 *= wd;
    if (WITH_BIAS_RELU) {
        a0 = fmaxf(a0 + bf2f(bias[2 * l]), 0.f);
        a1 = fmaxf(a1 + bf2f(bias[2 * l + 1]), 0.f);
    }
    ((uint32_t*)Yout)[(size_t)node * 64 + l] = packbf(a0, a1);
}

// ---------------- GEMM-2 + fused bias/relu/pool: pooled[g] += relu(Z@W2 + b2) ----------------
// B n-chunk staged in LDS (32KB); 32 rows/wave, 128 rows/block, grid (782, 2).

__global__ __launch_bounds__(256) void k_gemm2_pool(const uint16_t* __restrict__ A,   // Zb [M][128]
                                                    const uint16_t* __restrict__ BT,  // W2T [256][128]
                                                    const uint16_t* __restrict__ bias,// bc2 [256]
                                                    const int* __restrict__ bat,
                                                    const int* __restrict__ flags,
                                                    float* __restrict__ pooled) {
    const int M = N_NODES, K = HD1;
    __shared__ uint16_t Bs[128 * BPAD];               // 34 KB
    int t = threadIdx.x;
    int wave = t >> 6, lane = t & 63;
    int quad = lane >> 4, l16 = lane & 15;
    int m0 = blockIdx.x * 128 + wave * 32;
    int n0 = blockIdx.y * 128;

    // stage W2T[n0:n0+128][0:128] -> Bs
#pragma unroll
    for (int i = 0; i < 8; i++) {
        int flat = (i * 256 + t) * 8;
        int col = flat >> 7, kk = flat & 127;
        *(bf16x8*)(Bs + col * BPAD + kk) = *(const bf16x8*)(BT + (n0 + col) * K + kk);
    }
    __syncthreads();

    f32x4 acc[2][8];
#pragma unroll
    for (int a = 0; a < 2; a++)
#pragma unroll
        for (int b = 0; b < 8; b++) acc[a][b] = f32x4{0.f, 0.f, 0.f, 0.f};

    int arow[2];
#pragma unroll
    for (int mt = 0; mt < 2; mt++) {
        int r = m0 + mt * 16 + l16;
        arow[mt] = r < M ? r : M - 1;
    }

    bf16x8 af[2][4];
#pragma unroll
    for (int mt = 0; mt < 2; mt++)
#pragma unroll
        for (int ks = 0; ks < 4; ks++)
            af[mt][ks] = *(const bf16x8*)(A + arow[mt] * K + ks * 32 + quad * 8);

#pragma unroll
    for (int ks = 0; ks < 4; ks++) {
        bf16x8 bq[8];
#pragma unroll
        for (int nt = 0; nt < 8; nt++)
            bq[nt] = *(const bf16x8*)(Bs + (nt * 16 + l16) * BPAD + ks * 32 + quad * 8);
#pragma unroll
        for (int mt = 0; mt < 2; mt++)
#pragma unroll
            for (int nt = 0; nt < 8; nt++)
                acc[mt][nt] = __builtin_amdgcn_mfma_f32_16x16x32_bf16(af[mt][ks], bq[nt], acc[mt][nt], 0, 0, 0);
    }

    int sh = flags[1];
    float bv[8];
#pragma unroll
    for (int nt = 0; nt < 8; nt++) bv[nt] = bf2f(bias[n0 + nt * 16 + l16]);

    // M % 32 == 0 -> a wave's 32 rows are all-valid or all-invalid.
    if (m0 < M) {
        int gfirst = ld_idx(bat, m0, sh);
        int glast  = ld_idx(bat, m0 + 31, sh);
        if (gfirst == glast) {
#pragma unroll
            for (int nt = 0; nt < 8; nt++) {
                float s = 0.f;
#pragma unroll
                for (int mt = 0; mt < 2; mt++)
#pragma unroll
                    for (int reg = 0; reg < 4; reg++)
                        s += fmaxf(acc[mt][nt][reg] + bv[nt], 0.f);
                s += __shfl_xor(s, 16);
                s += __shfl_xor(s, 32);
                if (quad == 0)
                    atomicAdd(&pooled[gfirst * HD2 + n0 + nt * 16 + l16], s);
            }
        } else {
#pragma unroll
            for (int mt = 0; mt < 2; mt++) {
                int rb = m0 + mt * 16 + quad * 4;
#pragma unroll
                for (int reg = 0; reg < 4; reg++) {
                    int g = ld_idx(bat, rb + reg, sh);
#pragma unroll
                    for (int nt = 0; nt < 8; nt++)
                        atomicAdd(&pooled[g * HD2 + n0 + nt * 16 + l16],
                                  fmaxf(acc[mt][nt][reg] + bv[nt], 0.f));
                }
            }
        }
    }
}

// ---------------- final FC: out = relu(mean @ fcW + fcb), dual-dtype out ----------------

__global__ __launch_bounds__(512) void k_final(const float* __restrict__ pooled, const int* __restrict__ gcnt,
                                               const uint16_t* __restrict__ fcWc, const uint16_t* __restrict__ fcbc,
                                               void* __restrict__ out, const int* __restrict__ flags) {
    __shared__ float pm[HD2];
    int g = blockIdx.x, t = threadIdx.x;
    if (t < HD2) pm[t] = pooled[g * HD2 + t] / fmaxf((float)gcnt[g], 1.0f);
    __syncthreads();
    float acc = bf2f(fcbc[t]);
    for (int k = 0; k < HD2; k++) acc = fmaf(pm[k], bf2f(fcWc[k * OUT_DIM + t]), acc);
    acc = fmaxf(acc, 0.f);
    if (flags[0]) ((uint16_t*)out)[g * OUT_DIM + t] = (uint16_t)f2bf_bits(acc);
    else          ((float*)out)[g * OUT_DIM + t] = acc;
}

// ---------------- launcher ----------------

extern "C" void kernel_launch(void* const* d_in, const int* in_sizes, int n_in,
                              void* d_out, int out_size, void* d_ws, size_t ws_size,
                              hipStream_t stream) {
    const void* x   = d_in[0];               // [100000,256] bf16 or f32
    const int*  ei  = (const int*)d_in[1];   // [2,1600000] int32 or int64
    const int*  bat = (const int*)d_in[2];   // [100000]
    const void* W1  = d_in[3];               // [256,128]
    const void* b1  = d_in[4];               // [128]
    const void* W2  = d_in[5];               // [128,256]
    const void* b2  = d_in[6];               // [256]
    const void* fcW = d_in[7];               // [256,512]
    const void* fcb = d_in[8];               // [512]

    char* ws = (char*)d_ws;
    size_t off = 0;
    auto alloc = [&](size_t bytes) -> void* {
        void* p = ws + off;
        off += (bytes + 255) & ~(size_t)255;
        return p;
    };
    uint16_t* buf0 = (uint16_t*)alloc((size_t)N_NODES * HD1 * 2);   // Y1, later Zb
    uint16_t* Hb   = (uint16_t*)alloc((size_t)N_NODES * HD1 * 2);
    int*   row_ptr = (int*)alloc((N_NODES + 1) * 4);
    int*   csr_src = (int*)alloc((size_t)N_EDGES * 4);
    int*   tmp     = (int*)alloc((size_t)N_EDGES * 4);
    int*   bh      = (int*)alloc(NBLK * NBUCK * 4);
    int*   bhoff   = (int*)alloc(NBLK * NBUCK * 4);
    int*   bucket_cnt  = (int*)alloc(NBUCK * 4);
    int*   bucket_base = (int*)alloc((NBUCK + 1) * 4);
    float* dinv    = (float*)alloc(N_NODES * 4);
    int*   gcnt    = (int*)alloc(N_GRAPHS * 4);
    float* pooled  = (float*)alloc(N_GRAPHS * HD2 * 4);
    uint16_t* W1T  = (uint16_t*)alloc(IN_DIM * HD1 * 2);
    uint16_t* W2T  = (uint16_t*)alloc(HD1 * HD2 * 2);
    uint16_t* bc1  = (uint16_t*)alloc(HD1 * 2);
    uint16_t* bc2  = (uint16_t*)alloc(HD2 * 2);
    uint16_t* fcWc = (uint16_t*)alloc(HD2 * OUT_DIM * 2);
    uint16_t* fcbc = (uint16_t*)alloc(OUT_DIM * 2);
    int*   flags   = (int*)alloc(64 * 4);

    uint16_t* Y1 = buf0;
    uint16_t* Zb = buf0;   // Y1 dead after agg-1

    hipMemsetAsync(gcnt, 0, N_GRAPHS * 4, stream);
    hipMemsetAsync(pooled, 0, N_GRAPHS * HD2 * 4, stream);

    k_probe<<<1, 64, 0, stream>>>((const uint32_t*)x, ei, flags);

    // canonicalize weights/biases to bf16 (one fused kernel)
    k_prep<<<(197504 + 255) / 256, 256, 0, stream>>>(W1, W2, fcW, b1, b2, fcb,
                                                     W1T, W2T, fcWc, bc1, bc2, fcbc, flags);

    // CSR build: hist -> colscan -> bscan -> part -> bucket sort (no global atomics)
    k_hist<<<NBLK, 256, 0, stream>>>(ei, bh, flags);
    k_colscan<<<NBUCK, 256, 0, stream>>>(bh, bhoff, bucket_cnt);
    k_bscan<<<1, 256, 0, stream>>>(bucket_cnt, bucket_base, row_ptr);
    k_part<<<NBLK, 256, 0, stream>>>(ei, bucket_base, bhoff, tmp, flags);
    k_bsort<<<NBUCK, 256, 0, stream>>>(tmp, bucket_base, csr_src, row_ptr, dinv);

    k_gcnt<<<(N_NODES + 256 * GCNT_CHUNK - 1) / (256 * GCNT_CHUNK), 256, 0, stream>>>(bat, gcnt, flags);

    // layer 1: Y1 = X @ W1 ; H = relu(A Y1 + b1)
    k_gemm1<<<(N_NODES + 127) / 128, 256, 0, stream>>>(x, W1T, Y1, flags);
    k_agg<1><<<N_NODES / 4, 256, 0, stream>>>(Y1, Hb, row_ptr, csr_src, dinv, bc1);

    // layer 2 (aggregate-first): Z = A H ; pooled += relu(Z @ W2 + b2)
    k_agg<0><<<N_NODES / 4, 256, 0, stream>>>(Hb, Zb, row_ptr, csr_src, dinv, nullptr);
    k_gemm2_pool<<<dim3((N_NODES + 127) / 128, 2), 256, 0, stream>>>(Zb, W2T, bc2, bat, flags, pooled);

    // final FC
    k_final<<<N_GRAPHS, 512, 0, stream>>>(pooled, gcnt, fcWc, fcbc, d_out, flags);
}

// Round 8
// 421.038 us; speedup vs baseline: 1.1949x; 1.0001x over previous
//
#include <hip/hip_runtime.h>
#include <hip/hip_bf16.h>
#include <cstdint>

#define N_NODES 100000
#define N_EDGES 1600000
#define N_GRAPHS 64
#define IN_DIM 256
#define HD1 128
#define HD2 256
#define OUT_DIM 512

// CSR-build radix partition parameters
#define NBUCK 196          // ceil(100000/512) buckets of 512 dst nodes
#define NBLK  196          // edge-chunk blocks
#define EPB   8192         // edges per block (NBLK*EPB >= N_EDGES)

// LDS B-tile row pitch (elements): 128 + 8 pad -> balanced banks for ds_read_b128
#define BPAD 136

typedef __bf16 bf16x8 __attribute__((ext_vector_type(8)));
typedef float f32x4 __attribute__((ext_vector_type(4)));

static __device__ __forceinline__ float bflo(uint32_t v) { return __uint_as_float(v << 16); }
static __device__ __forceinline__ float bfhi(uint32_t v) { return __uint_as_float(v & 0xffff0000u); }
static __device__ __forceinline__ uint32_t f2bf_bits(float f) {
    uint32_t u = __float_as_uint(f);
    return (u + 0x7fffu + ((u >> 16) & 1u)) >> 16;   // RNE
}
static __device__ __forceinline__ uint32_t packbf(float a, float b) {
    return f2bf_bits(a) | (f2bf_bits(b) << 16);
}
static __device__ __forceinline__ float bf2f(uint16_t b) { return __uint_as_float(((uint32_t)b) << 16); }

// ---------------- runtime dtype probe ----------------
__global__ void k_probe(const uint32_t* __restrict__ xw, const int* __restrict__ ei,
                        int* __restrict__ flags) {
    if (threadIdx.x != 0 || blockIdx.x != 0) return;
    int mid = 0;
    for (int i = 0; i < 64; i++) {
        uint32_t f = (xw[i] >> 23) & 0xFF;
        if (f >= 64 && f < 200) mid++;
    }
    flags[0] = (mid < 32) ? 1 : 0;                  // bf16 vs f32
    int nz = 0;
    for (int i = 0; i < 64; i++) if (ei[2 * i + 1] != 0) nz++;
    flags[1] = (nz == 0) ? 1 : 0;                   // int64 vs int32
}

static __device__ __forceinline__ int ld_idx(const int* p, int i, int sh) { return p[i << sh]; }
static __device__ __forceinline__ float ld_f(const void* p, int i, int isbf) {
    return isbf ? bf2f(((const uint16_t*)p)[i]) : ((const float*)p)[i];
}

// ---------------- fused weight/bias canonicalization (bf16, transposed) ----------------
__global__ __launch_bounds__(256) void k_prep(const void* __restrict__ W1, const void* __restrict__ W2,
                                              const void* __restrict__ fcW, const void* __restrict__ b1,
                                              const void* __restrict__ b2, const void* __restrict__ fcb,
                                              uint16_t* __restrict__ W1T, uint16_t* __restrict__ W2T,
                                              uint16_t* __restrict__ fcWc, uint16_t* __restrict__ bc1,
                                              uint16_t* __restrict__ bc2, uint16_t* __restrict__ fcbc,
                                              const int* __restrict__ flags) {
    int i = blockIdx.x * 256 + threadIdx.x;
    int isbf = flags[0];
    if (i < 32768) {                                   // W1T[n][k] = W1[k][n], [128][256]
        int n = i / IN_DIM, k = i % IN_DIM;
        W1T[i] = (uint16_t)f2bf_bits(ld_f(W1, k * HD1 + n, isbf));
    } else if (i < 65536) {                            // W2T[n][k] = W2[k][n], [256][128]
        int j = i - 32768;
        int n = j / HD1, k = j % HD1;
        W2T[j] = (uint16_t)f2bf_bits(ld_f(W2, k * HD2 + n, isbf));
    } else if (i < 196608) {
        int j = i - 65536;
        fcWc[j] = (uint16_t)f2bf_bits(ld_f(fcW, j, isbf));
    } else if (i < 196736) {
        bc1[i - 196608] = (uint16_t)f2bf_bits(ld_f(b1, i - 196608, isbf));
    } else if (i < 196992) {
        bc2[i - 196736] = (uint16_t)f2bf_bits(ld_f(b2, i - 196736, isbf));
    } else if (i < 197504) {
        fcbc[i - 196992] = (uint16_t)f2bf_bits(ld_f(fcb, i - 196992, isbf));
    }
}

// ---------------- CSR build: atomic-free radix partition by dst bucket ----------------

__global__ __launch_bounds__(256) void k_hist(const int* __restrict__ ei, int* __restrict__ bh,
                                              const int* __restrict__ flags) {
    __shared__ int h[NBUCK];
    int t = threadIdx.x, blk = blockIdx.x;
    if (t < NBUCK) h[t] = 0;
    __syncthreads();
    int sh = flags[1];
    int base = blk * EPB;
#pragma unroll
    for (int k = 0; k < EPB / 256; k++) {
        int e = base + k * 256 + t;
        if (e < N_EDGES) atomicAdd(&h[ld_idx(ei, N_EDGES + e, sh) >> 9], 1);
    }
    __syncthreads();
    if (t < NBUCK) bh[blk * NBUCK + t] = h[t];
}

__global__ __launch_bounds__(256) void k_colscan(const int* __restrict__ bh, int* __restrict__ bhoff,
                                                 int* __restrict__ bucket_cnt) {
    __shared__ int s[256];
    int b = blockIdx.x, t = threadIdx.x;
    int v = (t < NBLK) ? bh[t * NBUCK + b] : 0;
    s[t] = v; __syncthreads();
    for (int off = 1; off < 256; off <<= 1) {
        int x = (t >= off) ? s[t - off] : 0;
        __syncthreads();
        s[t] += x;
        __syncthreads();
    }
    if (t < NBLK) bhoff[t * NBUCK + b] = s[t] - v;    // exclusive within bucket
    if (t == 255) bucket_cnt[b] = s[255];
}

__global__ __launch_bounds__(256) void k_bscan(const int* __restrict__ bucket_cnt,
                                               int* __restrict__ bucket_base,
                                               int* __restrict__ row_ptr) {
    __shared__ int s[256];
    int t = threadIdx.x;
    int v = (t < NBUCK) ? bucket_cnt[t] : 0;
    s[t] = v; __syncthreads();
    for (int off = 1; off < 256; off <<= 1) {
        int x = (t >= off) ? s[t - off] : 0;
        __syncthreads();
        s[t] += x;
        __syncthreads();
    }
    if (t < NBUCK) bucket_base[t] = s[t] - v;
    if (t == NBUCK - 1) { bucket_base[NBUCK] = s[t]; row_ptr[N_NODES] = s[t]; }
}

__global__ __launch_bounds__(256) void k_part(const int* __restrict__ ei,
                                              const int* __restrict__ bucket_base,
                                              const int* __restrict__ bhoff,
                                              int* __restrict__ tmp,
                                              const int* __restrict__ flags) {
    __shared__ int cur[NBUCK];
    int t = threadIdx.x, blk = blockIdx.x;
    if (t < NBUCK) cur[t] = bucket_base[t] + bhoff[blk * NBUCK + t];
    __syncthreads();
    int sh = flags[1];
    int base = blk * EPB;
#pragma unroll
    for (int k = 0; k < EPB / 256; k++) {
        int e = base + k * 256 + t;
        if (e < N_EDGES) {
            int s = ld_idx(ei, e, sh), d = ld_idx(ei, N_EDGES + e, sh);
            int pos = atomicAdd(&cur[d >> 9], 1);
            tmp[pos] = (s << 9) | (d & 511);          // s<2^17 -> 26-bit key
        }
    }
}

__global__ __launch_bounds__(256) void k_bsort(const int* __restrict__ tmp,
                                               const int* __restrict__ bucket_base,
                                               int* __restrict__ csr_src,
                                               int* __restrict__ row_ptr,
                                               float* __restrict__ dinv) {
    __shared__ int h[512], a[512], c[512];
    int b = blockIdx.x, t = threadIdx.x;
    int beg = bucket_base[b], end = bucket_base[b + 1];
    h[t] = 0; h[t + 256] = 0;
    __syncthreads();
    for (int i = beg + t; i < end; i += 256) atomicAdd(&h[tmp[i] & 511], 1);
    __syncthreads();
    a[t] = h[t]; a[t + 256] = h[t + 256];
    __syncthreads();
    for (int off = 1; off < 512; off <<= 1) {
        int x0 = (t >= off) ? a[t - off] : 0;
        int x1 = ((t + 256) >= off) ? a[t + 256 - off] : 0;
        __syncthreads();
        a[t] += x0; a[t + 256] += x1;
        __syncthreads();
    }
#pragma unroll
    for (int u = 0; u < 2; u++) {
        int i = t + u * 256;
        int node = (b << 9) + i;
        int ex = a[i] - h[i];
        if (node < N_NODES) {
            row_ptr[node] = beg + ex;
            dinv[node] = rsqrtf((float)(h[i] + 1));   // +1 self-loop
        }
        c[i] = ex;
    }
    __syncthreads();
    for (int i = beg + t; i < end; i += 256) {
        int e = tmp[i];
        int pos = atomicAdd(&c[e & 511], 1);
        csr_src[beg + pos] = e >> 9;
    }
}

// ---------------- per-graph node counts ----------------
#define GCNT_CHUNK 8
__global__ __launch_bounds__(256) void k_gcnt(const int* __restrict__ bat, int* __restrict__ gcnt,
                                              const int* __restrict__ flags) {
    __shared__ int h[N_GRAPHS];
    int t = threadIdx.x;
    if (t < N_GRAPHS) h[t] = 0;
    __syncthreads();
    int sh = flags[1];
    int base = (blockIdx.x * 256 + t) * GCNT_CHUNK;
    int cur = -1, run = 0;
#pragma unroll
    for (int u = 0; u < GCNT_CHUNK; u++) {
        int i = base + u;
        if (i < N_NODES) {
            int g = ld_idx(bat, i, sh);
            if (g == cur) run++;
            else { if (run) atomicAdd(&h[cur], run); cur = g; run = 1; }
        }
    }
    if (run) atomicAdd(&h[cur], run);
    __syncthreads();
    if (t < N_GRAPHS) { int v = h[t]; if (v) atomicAdd(&gcnt[t], v); }
}

// ---------------- GEMM-1: Y1[M,128] = X[M,256] @ W1 ----------------
// B staged in LDS (two 32KB K-halves); 32 rows/wave, 128 rows/block.

__global__ __launch_bounds__(256) void k_gemm1(const void* __restrict__ Ain,
                                               const uint16_t* __restrict__ BT,  // [128][256] bf16
                                               uint16_t* __restrict__ C,
                                               const int* __restrict__ flags) {
    const int M = N_NODES, K = IN_DIM, N = HD1;
    __shared__ uint16_t Bs[HD1 * BPAD];               // 128 x 136 bf16 = 34 KB
    int isbf = flags[0];
    int t = threadIdx.x;
    int wave = t >> 6, lane = t & 63;
    int quad = lane >> 4, l16 = lane & 15;
    int m0 = blockIdx.x * 128 + wave * 32;

    f32x4 acc[2][8];
#pragma unroll
    for (int a = 0; a < 2; a++)
#pragma unroll
        for (int b = 0; b < 8; b++) acc[a][b] = f32x4{0.f, 0.f, 0.f, 0.f};

    int arow[2];
#pragma unroll
    for (int mt = 0; mt < 2; mt++) {
        int r = m0 + mt * 16 + l16;
        arow[mt] = r < M ? r : M - 1;                 // clamp; store guarded
    }

#pragma unroll
    for (int half = 0; half < 2; half++) {
        int kb = half * 128;
#pragma unroll
        for (int i = 0; i < 8; i++) {
            int flat = (i * 256 + t) * 8;             // 0..16383
            int col = flat >> 7, kk = flat & 127;
            *(bf16x8*)(Bs + col * BPAD + kk) = *(const bf16x8*)(BT + col * K + kb + kk);
        }
        __syncthreads();

        bf16x8 af[2][4];
#pragma unroll
        for (int mt = 0; mt < 2; mt++)
#pragma unroll
            for (int ks = 0; ks < 4; ks++) {
                int off = arow[mt] * K + kb + ks * 32 + quad * 8;
                if (isbf) {
                    af[mt][ks] = *(const bf16x8*)((const uint16_t*)Ain + off);
                } else {
                    const float* p = (const float*)Ain + off;
                    f32x4 f0 = *(const f32x4*)p, f1 = *(const f32x4*)(p + 4);
                    union { uint16_t u[8]; bf16x8 v; } r;
#pragma unroll
                    for (int j = 0; j < 4; j++) {
                        r.u[j]     = (uint16_t)f2bf_bits(f0[j]);
                        r.u[4 + j] = (uint16_t)f2bf_bits(f1[j]);
                    }
                    af[mt][ks] = r.v;
                }
            }

#pragma unroll
        for (int ks = 0; ks < 4; ks++) {
            bf16x8 bq[8];
#pragma unroll
            for (int nt = 0; nt < 8; nt++)
                bq[nt] = *(const bf16x8*)(Bs + (nt * 16 + l16) * BPAD + ks * 32 + quad * 8);
#pragma unroll
            for (int mt = 0; mt < 2; mt++)
#pragma unroll
                for (int nt = 0; nt < 8; nt++)
                    acc[mt][nt] = __builtin_amdgcn_mfma_f32_16x16x32_bf16(af[mt][ks], bq[nt], acc[mt][nt], 0, 0, 0);
        }
        __syncthreads();                              // before next half overwrites Bs
    }

#pragma unroll
    for (int mt = 0; mt < 2; mt++)
#pragma unroll
        for (int reg = 0; reg < 4; reg++) {
            int row = m0 + mt * 16 + quad * 4 + reg;  // C/D: col=lane&15, row=quad*4+reg
            if (row < M)
#pragma unroll
                for (int nt = 0; nt < 8; nt++)
                    C[row * N + nt * 16 + l16] = (uint16_t)f2bf_bits(acc[mt][nt][reg]);
        }
}

// ---------------- aggregation (wave-cooperative; readlane broadcast, 16-deep gather) ----------------
// out[d] = dinv[d] * (sum_src dinv[s]*Y[s] + dinv[d]*Y[d]) [+bias, relu]
// v_readlane (uniform index) -> SGPR src + scalar addressing: no ds_bpermute LDS-pipe traffic.

template <int WITH_BIAS_RELU>
__global__ __launch_bounds__(256) void k_agg(const uint16_t* __restrict__ Yin, uint16_t* __restrict__ Yout,
                                             const int* __restrict__ row_ptr, const int* __restrict__ csr_src,
                                             const float* __restrict__ dinv, const uint16_t* __restrict__ bias) {
    int node = blockIdx.x * 4 + (threadIdx.x >> 6);
    int l = threadIdx.x & 63;
    const uint32_t* Y32 = (const uint32_t*)Yin;

    float wd = dinv[node];
    uint32_t v = Y32[(size_t)node * 64 + l];
    float a0 = wd * bflo(v), a1 = wd * bfhi(v);

    int e0 = row_ptr[node], e1 = row_ptr[node + 1];
    for (int cb = e0; cb < e1; cb += 64) {
        int cnt = e1 - cb; if (cnt > 64) cnt = 64;
        // lane-parallel prefetch of indices + weights (1 coalesced load + 1 gather)
        int my_src = 0; uint32_t my_w = 0;            // lanes >= cnt: w=0 -> contribute 0, read row 0
        if (l < cnt) { my_src = csr_src[cb + l]; my_w = __float_as_uint(dinv[my_src]); }
        int rounds = (cnt + 15) >> 4;
        for (int r = 0; r < rounds; r++) {
            int jb = r * 16;
            uint32_t vv[16];
#pragma unroll
            for (int t = 0; t < 16; t++) {
                int s = __builtin_amdgcn_readlane(my_src, jb + t);   // SGPR: scalar addr math
                vv[t] = Y32[(size_t)s * 64 + l];
            }
#pragma unroll
            for (int t = 0; t < 16; t++) {
                float w = __uint_as_float(__builtin_amdgcn_readlane(my_w, jb + t));
                a0 += w * bflo(vv[t]);
                a1 += w * bfhi(vv[t]);
            }
        }
    }
    a0 *= wd; a1 *= wd;
    if (WITH_BIAS_RELU) {
        a0 = fmaxf(a0 + bf2f(bias[2 * l]), 0.f);
        a1 = fmaxf(a1 + bf2f(bias[2 * l + 1]), 0.f);
    }
    ((uint32_t*)Yout)[(size_t)node * 64 + l] = packbf(a0, a1);
}

// ---------------- GEMM-2 + fused bias/relu/pool: pooled[g] += relu(Z@W2 + b2) ----------------

__global__ __launch_bounds__(256) void k_gemm2_pool(const uint16_t* __restrict__ A,   // Zb [M][128]
                                                    const uint16_t* __restrict__ BT,  // W2T [256][128]
                                                    const uint16_t* __restrict__ bias,// bc2 [256]
                                                    const int* __restrict__ bat,
                                                    const int* __restrict__ flags,
                                                    float* __restrict__ pooled) {
    const int M = N_NODES, K = HD1;
    __shared__ uint16_t Bs[128 * BPAD];               // 34 KB
    int t = threadIdx.x;
    int wave = t >> 6, lane = t & 63;
    int quad = lane >> 4, l16 = lane & 15;
    int m0 = blockIdx.x * 128 + wave * 32;
    int n0 = blockIdx.y * 128;

#pragma unroll
    for (int i = 0; i < 8; i++) {
        int flat = (i * 256 + t) * 8;
        int col = flat >> 7, kk = flat & 127;
        *(bf16x8*)(Bs + col * BPAD + kk) = *(const bf16x8*)(BT + (n0 + col) * K + kk);
    }
    __syncthreads();

    f32x4 acc[2][8];
#pragma unroll
    for (int a = 0; a < 2; a++)
#pragma unroll
        for (int b = 0; b < 8; b++) acc[a][b] = f32x4{0.f, 0.f, 0.f, 0.f};

    int arow[2];
#pragma unroll
    for (int mt = 0; mt < 2; mt++) {
        int r = m0 + mt * 16 + l16;
        arow[mt] = r < M ? r : M - 1;
    }

    bf16x8 af[2][4];
#pragma unroll
    for (int mt = 0; mt < 2; mt++)
#pragma unroll
        for (int ks = 0; ks < 4; ks++)
            af[mt][ks] = *(const bf16x8*)(A + arow[mt] * K + ks * 32 + quad * 8);

#pragma unroll
    for (int ks = 0; ks < 4; ks++) {
        bf16x8 bq[8];
#pragma unroll
        for (int nt = 0; nt < 8; nt++)
            bq[nt] = *(const bf16x8*)(Bs + (nt * 16 + l16) * BPAD + ks * 32 + quad * 8);
#pragma unroll
        for (int mt = 0; mt < 2; mt++)
#pragma unroll
            for (int nt = 0; nt < 8; nt++)
                acc[mt][nt] = __builtin_amdgcn_mfma_f32_16x16x32_bf16(af[mt][ks], bq[nt], acc[mt][nt], 0, 0, 0);
    }

    int sh = flags[1];
    float bv[8];
#pragma unroll
    for (int nt = 0; nt < 8; nt++) bv[nt] = bf2f(bias[n0 + nt * 16 + l16]);

    // M % 32 == 0 -> a wave's 32 rows are all-valid or all-invalid.
    if (m0 < M) {
        int gfirst = ld_idx(bat, m0, sh);
        int glast  = ld_idx(bat, m0 + 31, sh);
        if (gfirst == glast) {
#pragma unroll
            for (int nt = 0; nt < 8; nt++) {
                float s = 0.f;
#pragma unroll
                for (int mt = 0; mt < 2; mt++)
#pragma unroll
                    for (int reg = 0; reg < 4; reg++)
                        s += fmaxf(acc[mt][nt][reg] + bv[nt], 0.f);
                s += __shfl_xor(s, 16);
                s += __shfl_xor(s, 32);
                if (quad == 0)
                    atomicAdd(&pooled[gfirst * HD2 + n0 + nt * 16 + l16], s);
            }
        } else {
#pragma unroll
            for (int mt = 0; mt < 2; mt++) {
                int rb = m0 + mt * 16 + quad * 4;
#pragma unroll
                for (int reg = 0; reg < 4; reg++) {
                    int g = ld_idx(bat, rb + reg, sh);
#pragma unroll
                    for (int nt = 0; nt < 8; nt++)
                        atomicAdd(&pooled[g * HD2 + n0 + nt * 16 + l16],
                                  fmaxf(acc[mt][nt][reg] + bv[nt], 0.f));
                }
            }
        }
    }
}

// ---------------- final FC: out = relu(mean @ fcW + fcb), dual-dtype out ----------------

__global__ __launch_bounds__(512) void k_final(const float* __restrict__ pooled, const int* __restrict__ gcnt,
                                               const uint16_t* __restrict__ fcWc, const uint16_t* __restrict__ fcbc,
                                               void* __restrict__ out, const int* __restrict__ flags) {
    __shared__ float pm[HD2];
    int g = blockIdx.x, t = threadIdx.x;
    if (t < HD2) pm[t] = pooled[g * HD2 + t] / fmaxf((float)gcnt[g], 1.0f);
    __syncthreads();
    float acc = bf2f(fcbc[t]);
    for (int k = 0; k < HD2; k++) acc = fmaf(pm[k], bf2f(fcWc[k * OUT_DIM + t]), acc);
    acc = fmaxf(acc, 0.f);
    if (flags[0]) ((uint16_t*)out)[g * OUT_DIM + t] = (uint16_t)f2bf_bits(acc);
    else          ((float*)out)[g * OUT_DIM + t] = acc;
}

// ---------------- launcher ----------------

extern "C" void kernel_launch(void* const* d_in, const int* in_sizes, int n_in,
                              void* d_out, int out_size, void* d_ws, size_t ws_size,
                              hipStream_t stream) {
    const void* x   = d_in[0];               // [100000,256] bf16 or f32
    const int*  ei  = (const int*)d_in[1];   // [2,1600000] int32 or int64
    const int*  bat = (const int*)d_in[2];   // [100000]
    const void* W1  = d_in[3];               // [256,128]
    const void* b1  = d_in[4];               // [128]
    const void* W2  = d_in[5];               // [128,256]
    const void* b2  = d_in[6];               // [256]
    const void* fcW = d_in[7];               // [256,512]
    const void* fcb = d_in[8];               // [512]

    char* ws = (char*)d_ws;
    size_t off = 0;
    auto alloc = [&](size_t bytes) -> void* {
        void* p = ws + off;
        off += (bytes + 255) & ~(size_t)255;
        return p;
    };
    uint16_t* buf0 = (uint16_t*)alloc((size_t)N_NODES * HD1 * 2);   // Y1, later Zb
    uint16_t* Hb   = (uint16_t*)alloc((size_t)N_NODES * HD1 * 2);
    int*   row_ptr = (int*)alloc((N_NODES + 1) * 4);
    int*   csr_src = (int*)alloc((size_t)N_EDGES * 4);
    int*   tmp     = (int*)alloc((size_t)N_EDGES * 4);
    int*   bh      = (int*)alloc(NBLK * NBUCK * 4);
    int*   bhoff   = (int*)alloc(NBLK * NBUCK * 4);
    int*   bucket_cnt  = (int*)alloc(NBUCK * 4);
    int*   bucket_base = (int*)alloc((NBUCK + 1) * 4);
    float* dinv    = (float*)alloc(N_NODES * 4);
    int*   gcnt    = (int*)alloc(N_GRAPHS * 4);
    float* pooled  = (float*)alloc(N_GRAPHS * HD2 * 4);
    uint16_t* W1T  = (uint16_t*)alloc(IN_DIM * HD1 * 2);
    uint16_t* W2T  = (uint16_t*)alloc(HD1 * HD2 * 2);
    uint16_t* bc1  = (uint16_t*)alloc(HD1 * 2);
    uint16_t* bc2  = (uint16_t*)alloc(HD2 * 2);
    uint16_t* fcWc = (uint16_t*)alloc(HD2 * OUT_DIM * 2);
    uint16_t* fcbc = (uint16_t*)alloc(OUT_DIM * 2);
    int*   flags   = (int*)alloc(64 * 4);

    uint16_t* Y1 = buf0;
    uint16_t* Zb = buf0;   // Y1 dead after agg-1

    hipMemsetAsync(gcnt, 0, N_GRAPHS * 4, stream);
    hipMemsetAsync(pooled, 0, N_GRAPHS * HD2 * 4, stream);

    k_probe<<<1, 64, 0, stream>>>((const uint32_t*)x, ei, flags);

    // canonicalize weights/biases to bf16 (one fused kernel)
    k_prep<<<(197504 + 255) / 256, 256, 0, stream>>>(W1, W2, fcW, b1, b2, fcb,
                                                     W1T, W2T, fcWc, bc1, bc2, fcbc, flags);

    // CSR build: hist -> colscan -> bscan -> part -> bucket sort (no global atomics)
    k_hist<<<NBLK, 256, 0, stream>>>(ei, bh, flags);
    k_colscan<<<NBUCK, 256, 0, stream>>>(bh, bhoff, bucket_cnt);
    k_bscan<<<1, 256, 0, stream>>>(bucket_cnt, bucket_base, row_ptr);
    k_part<<<NBLK, 256, 0, stream>>>(ei, bucket_base, bhoff, tmp, flags);
    k_bsort<<<NBUCK, 256, 0, stream>>>(tmp, bucket_base, csr_src, row_ptr, dinv);

    k_gcnt<<<(N_NODES + 256 * GCNT_CHUNK - 1) / (256 * GCNT_CHUNK), 256, 0, stream>>>(bat, gcnt, flags);

    // layer 1: Y1 = X @ W1 ; H = relu(A Y1 + b1)
    k_gemm1<<<(N_NODES + 127) / 128, 256, 0, stream>>>(x, W1T, Y1, flags);
    k_agg<1><<<N_NODES / 4, 256, 0, stream>>>(Y1, Hb, row_ptr, csr_src, dinv, bc1);

    // layer 2 (aggregate-first): Z = A H ; pooled += relu(Z @ W2 + b2)
    k_agg<0><<<N_NODES / 4, 256, 0, stream>>>(Hb, Zb, row_ptr, csr_src, dinv, nullptr);
    k_gemm2_pool<<<dim3((N_NODES + 127) / 128, 2), 256, 0, stream>>>(Zb, W2T, bc2, bat, flags, pooled);

    // final FC
    k_final<<<N_GRAPHS, 512, 0, stream>>>(pooled, gcnt, fcWc, fcbc, d_out, flags);
}